// Round 1
// 736.974 us; speedup vs baseline: 1.0210x; 1.0210x over previous
//
#include <hip/hip_runtime.h>
#include <stdint.h>

#define B_SZ 1024
#define F_SZ 104013
#define NFIELD 39
#define N_RAW 312
#define N_PAD 320
#define KB_STEPS 3251            // ceil(104013 / 32)
#define PART_ELEMS ((size_t)B_SZ * N_PAD)

using bf16x8 = __attribute__((ext_vector_type(8))) short;
using f32x4  = __attribute__((ext_vector_type(4))) float;

typedef __attribute__((address_space(3))) void* lds_vp;
typedef const __attribute__((address_space(1))) void* glb_cvp;

__device__ __forceinline__ void ld16(const void* g, void* l) {
  // async global->LDS DMA, 16B per lane; LDS dest = uniform base + lane*16
  __builtin_amdgcn_global_load_lds((glb_cvp)g, (lds_vp)l, 16, 0, 0);
}

__device__ __forceinline__ unsigned int pack_bf16(float a, float b) {
  // round-half-up to bf16, pack two into one dword (lo = a, hi = b)
  unsigned int ua = __float_as_uint(a) + 0x8000u;
  unsigned int ub = __float_as_uint(b) + 0x8000u;
  return (ua >> 16) | (ub & 0xffff0000u);
}

// ---------------------------------------------------------------------------
// Kernel 1: transpose+convert v (plus w as column 312, zero pad to 320) into
// MFMA B-fragment order: chunk index (kb*20+nt)*64 + lane holds 8 bf16 with
// B[k = kb*32 + (lane>>4)*8 + j][n = nt*16 + (lane&15)], 16B per lane.
// Rows with k >= F_SZ are zero (protects GEMM tail).
// ---------------------------------------------------------------------------
__global__ __launch_bounds__(256) void pack_v(const float* __restrict__ v,
                                              const float* __restrict__ w,
                                              uint4* __restrict__ Bp) {
  const int kb = blockIdx.x;
  const int t  = threadIdx.x;
  __shared__ float vs[32][324];

  for (int idx = t; idx < 32 * 78; idx += 256) {
    int r = idx / 78, c4 = (idx % 78) * 4;
    int k = kb * 32 + r;
    float4 val = make_float4(0.f, 0.f, 0.f, 0.f);
    if (k < F_SZ) val = *(const float4*)(v + (size_t)k * N_RAW + c4);
    *(float4*)&vs[r][c4] = val;
  }
  if (t < 32) {
    int k = kb * 32 + t;
    vs[t][312] = (k < F_SZ) ? w[k] : 0.f;
#pragma unroll
    for (int c = 313; c < 320; ++c) vs[t][c] = 0.f;
  }
  __syncthreads();

#pragma unroll
  for (int i = 0; i < 5; ++i) {
    int p  = t + 256 * i;          // p = nt*64 + lane
    int l  = p & 63;
    int kr = (l >> 4) * 8;
    int col = (p >> 6) * 16 + (l & 15);
    uint4 o;
    o.x = pack_bf16(vs[kr + 0][col], vs[kr + 1][col]);
    o.y = pack_bf16(vs[kr + 2][col], vs[kr + 3][col]);
    o.z = pack_bf16(vs[kr + 4][col], vs[kr + 5][col]);
    o.w = pack_bf16(vs[kr + 6][col], vs[kr + 7][col]);
    Bp[(size_t)kb * 1280 + p] = o;
  }
}

// ---------------------------------------------------------------------------
// Kernel 2: split-K MFMA GEMM, v2.
// Block: 8 waves (512 thr), tile 128 rows x 320 cols; wave = 64 rows x 80 cols
// (acc[4][5] = 80 VGPR/lane). A is reg-staged: thread loads 8 f32, converts
// to bf16 ONCE, ds_write_b128 into [row][40 bf16] tile with seg^(row&3) XOR
// swizzle (bank-balanced: exactly 8 dwords/bank on both write and read).
// B staged via global_load_lds (already fragment-ordered bf16).
// Grid (S, 8): linear id % 8 == s % 8, so all 8 mt-peers of a k-slice share
// one XCD -> B slice is L2-local. LDS 60 KB dbuf, 1 block/CU, 2 waves/SIMD.
// ---------------------------------------------------------------------------
#define LDS_BUF 30720            // A: 128*80 = 10240 | B: 20*1024 = 20480
#define B_OFF   10240

__global__ __launch_bounds__(512, 2) void gemm_split(const float* __restrict__ A,
                                                     const uint4* __restrict__ Bp,
                                                     float* __restrict__ part) {
  const int S  = gridDim.x;
  const int s  = blockIdx.x, mt = blockIdx.y;
  const int t  = threadIdx.x;
  const int w  = t >> 6, l = t & 63;
  const int wr = w >> 2, wc = w & 3;
  const int lm = l & 15, lq = l >> 4;
  const int row0 = mt * 128;
  const int kb0 = (int)((long long)KB_STEPS * s / S);
  const int kb1 = (int)((long long)KB_STEPS * (s + 1) / S);

  __shared__ __align__(16) char smem[2][LDS_BUF];

  // A staging geometry: thread owns (srow = t>>2, seg = t&3): 8 consecutive
  // f32 of A[row0+srow][kb*32 + seg*8 ..+8), written as 8 bf16 (16B) to
  // LDS offset srow*80 + (seg ^ (srow&3))*16.
  const int srow = t >> 2, seg = t & 3;
  const float* ag = A + (size_t)(row0 + srow) * F_SZ + seg * 8;
  const int wswz = srow * 80 + ((seg ^ (srow & 3)) << 4);

  auto loadA = [&](int kb, float4& d0, float4& d1) {
    const float* ap = ag + (size_t)kb * 32;
    if (kb != KB_STEPS - 1) {
      d0 = *(const float4*)(ap);
      d1 = *(const float4*)(ap + 4);
    } else {  // tail kb: k range may exceed F_SZ, guard each element
      const int kbase = kb * 32 + seg * 8;
      float f[8];
#pragma unroll
      for (int e = 0; e < 8; ++e) f[e] = (kbase + e < F_SZ) ? ap[e] : 0.f;
      d0 = make_float4(f[0], f[1], f[2], f[3]);
      d1 = make_float4(f[4], f[5], f[6], f[7]);
    }
  };

  auto writeA = [&](int buf, const float4& d0, const float4& d1) {
    uint4 pk;
    pk.x = pack_bf16(d0.x, d0.y);
    pk.y = pack_bf16(d0.z, d0.w);
    pk.z = pack_bf16(d1.x, d1.y);
    pk.w = pack_bf16(d1.z, d1.w);
    *(uint4*)(smem[buf] + wswz) = pk;
  };

  auto stageB = [&](int kb, int buf) {
    for (int c = w; c < 20; c += 8)
      ld16(Bp + ((size_t)kb * 20 + c) * 64 + l, smem[buf] + B_OFF + c * 1024);
  };

  f32x4 acc[4][5];
#pragma unroll
  for (int i = 0; i < 4; ++i)
#pragma unroll
    for (int n = 0; n < 5; ++n) acc[i][n] = (f32x4)0.f;

  auto compute = [&](int buf) {
    const char* bs = smem[buf];
    bf16x8 af[4];
#pragma unroll
    for (int i = 0; i < 4; ++i)
      af[i] = __builtin_bit_cast(
          bf16x8, *(const uint4*)(bs + (wr * 64 + i * 16 + lm) * 80 +
                                  ((lq ^ (lm & 3)) << 4)));
#pragma unroll
    for (int n = 0; n < 5; ++n) {
      bf16x8 bf = __builtin_bit_cast(
          bf16x8, *(const uint4*)(bs + B_OFF + (wc * 5 + n) * 1024 + l * 16));
#pragma unroll
      for (int i = 0; i < 4; ++i)
        acc[i][n] = __builtin_amdgcn_mfma_f32_16x16x32_bf16(af[i], bf,
                                                            acc[i][n], 0, 0, 0);
    }
  };

  // Prologue: set a = kb0 (issue loads, stage buf0), set b = kb0+1 prefetch.
  float4 a0, a1, b0, b1;
  loadA(kb0, a0, a1);                     // oldest vmem: a-set
  stageB(kb0, 0);                         // B DMA after (writeA waits only a-set)
  writeA(0, a0, a1);
  if (kb0 + 1 < kb1) loadA(kb0 + 1, b0, b1);
  __syncthreads();                        // drains everything; buf0 ready

  // Main loop: per kb, stage kb+1 into buf^1 from the prefetched reg set
  // (landed: previous barrier drained vmcnt), issue kb+2 loads into the other
  // set, then compute buf[cur]. Barrier at end publishes buf^1 + paces HBM.
  int kb = kb0, cur = 0;
  while (true) {
    if (kb + 1 < kb1) {
      stageB(kb + 1, cur ^ 1);
      writeA(cur ^ 1, b0, b1);
      if (kb + 2 < kb1) loadA(kb + 2, a0, a1);
    }
    compute(cur);
    __syncthreads();
    ++kb; cur ^= 1;
    if (kb >= kb1) break;

    if (kb + 1 < kb1) {
      stageB(kb + 1, cur ^ 1);
      writeA(cur ^ 1, a0, a1);
      if (kb + 2 < kb1) loadA(kb + 2, b0, b1);
    }
    compute(cur);
    __syncthreads();
    ++kb; cur ^= 1;
    if (kb >= kb1) break;
  }

  // epilogue: C/D layout col = lane&15, row = (lane>>4)*4 + reg
  float* outp = part + (size_t)s * PART_ELEMS;
#pragma unroll
  for (int i = 0; i < 4; ++i) {
    int rb = row0 + wr * 64 + i * 16 + lq * 4;
#pragma unroll
    for (int n = 0; n < 5; ++n) {
      int col = (wc * 5 + n) * 16 + lm;
#pragma unroll
      for (int r = 0; r < 4; ++r)
        outp[(size_t)(rb + r) * N_PAD + col] = acc[i][n][r];
    }
  }
}

// ---------------------------------------------------------------------------
// Kernel 3: per-row reduction of S partial slabs + FM epilogue.
// 320 threads: one column each (coalesced 1280B per slab row).
// out[b] = w0 + C[b][312] + 0.5*(sum_k (sum_f C[b][8f+k])^2 - sum_{n<312} C^2)
// ---------------------------------------------------------------------------
__global__ __launch_bounds__(320) void finalize(const float* __restrict__ part,
                                                const float* __restrict__ w0,
                                                float* __restrict__ out, int S) {
  const int b = blockIdx.x;
  const int t = threadIdx.x;
  __shared__ float crow[N_PAD];
  __shared__ float red[5];
  __shared__ float skl[8];

  float acc = 0.f;
  const float* p = part + (size_t)b * N_PAD + t;
#pragma unroll 4
  for (int s = 0; s < S; ++s) acc += p[(size_t)s * PART_ELEMS];
  crow[t] = acc;

  float sq = (t < N_RAW) ? acc * acc : 0.f;
#pragma unroll
  for (int off = 32; off; off >>= 1) sq += __shfl_down(sq, off);
  if ((t & 63) == 0) red[t >> 6] = sq;
  __syncthreads();

  if (t < 8) {
    float sk = 0.f;
#pragma unroll
    for (int f = 0; f < NFIELD; ++f) sk += crow[f * 8 + t];
    skl[t] = sk;
  }
  __syncthreads();
  if (t == 0) {
    float sumsq = red[0] + red[1] + red[2] + red[3] + red[4];
    float ss = 0.f;
#pragma unroll
    for (int k = 0; k < 8; ++k) ss += skl[k] * skl[k];
    out[b] = w0[0] + crow[312] + 0.5f * (ss - sumsq);
  }
}

extern "C" void kernel_launch(void* const* d_in, const int* in_sizes, int n_in,
                              void* d_out, int out_size, void* d_ws, size_t ws_size,
                              hipStream_t stream) {
  const float* inputs = (const float*)d_in[0];
  const float* w0 = (const float*)d_in[1];
  const float* w  = (const float*)d_in[2];
  const float* v  = (const float*)d_in[3];
  float* out = (float*)d_out;

  const size_t PART_BYTES   = PART_ELEMS * sizeof(float);           // 1.31 MB
  const size_t PACKED_BYTES = (size_t)KB_STEPS * 20 * 64 * 16;      // 66.6 MB
  int S = 32;
  while (S > 1 && PACKED_BYTES + (size_t)S * PART_BYTES > ws_size) S >>= 1;

  float* part = (float*)d_ws;
  uint4* Bp   = (uint4*)((char*)d_ws + (size_t)S * PART_BYTES);

  pack_v<<<dim3(KB_STEPS), 256, 0, stream>>>(v, w, Bp);
  gemm_split<<<dim3(S, 8), 512, 0, stream>>>(inputs, Bp, part);
  finalize<<<dim3(B_SZ), 320, 0, stream>>>(part, w0, out, S);
}